// Round 16
// baseline (97.903 us; speedup 1.0000x reference)
//
#include <hip/hip_runtime.h>
#include <hip/hip_bf16.h>
#include <math.h>

#define L_SEQ 1024
#define TWO_L 2048
#define NHEAD 16
#define HD 64
#define DM 1024
#define BATCH 2
// pe2: 2176 rows, row r <-> u = r-1088, value = pe_ext[u mod 2049];
// pe_ext[j] = pe[j] for j<2048, pe_ext[2048] = 0 (shifted-diagonal zero row).
#define PE2R 2176
#define GBS 132

typedef _Float16 f16;
typedef _Float16 f16x4 __attribute__((ext_vector_type(4)));
typedef _Float16 f16x8 __attribute__((ext_vector_type(8)));
typedef float f32x4 __attribute__((ext_vector_type(4)));

__device__ __forceinline__ f16x8 ld8(const f16* p) {
  f16x4 lo = *(const f16x4*)p;
  f16x4 hi = *(const f16x4*)(p + 16);
  f16x8 r;
  r[0] = lo[0]; r[1] = lo[1]; r[2] = lo[2]; r[3] = lo[3];
  r[4] = hi[0]; r[5] = hi[1]; r[6] = hi[2]; r[7] = hi[3];
  return r;
}

__device__ __forceinline__ float pe_val(int j, int d) {
  float posval = (float)(j - L_SEQ);
  float freq = expf(-(float)(d & 31) * 0.2971077539347156f);  // ln(10000)/31
  float ang = posval * freq;
  return (d < 32) ? sinf(ang) : cosf(ang);
}

// ---------------- prep1: cvt x, cvt W, pe2 extended table ----------------
__global__ __launch_bounds__(256) void prep1(const float* __restrict__ x,
                                             const float* __restrict__ W,
                                             f16* __restrict__ pe2,
                                             f16* __restrict__ xh,
                                             f16* __restrict__ Wh) {
  int bid = blockIdx.x, tid = threadIdx.x;
  if (bid < 2048) {
    int i = (bid * 256 + tid) * 4;
    float4 v = *(const float4*)(x + i);
    f16x4 o = {(f16)v.x, (f16)v.y, (f16)v.z, (f16)v.w};
    *(f16x4*)(xh + i) = o;
  } else if (bid < 4096) {
    int i = ((bid - 2048) * 256 + tid) * 4;
    float4 v = *(const float4*)(W + i);
    f16x4 o = {(f16)v.x, (f16)v.y, (f16)v.z, (f16)v.w};
    *(f16x4*)(Wh + i) = o;
  } else {
    int idx = (bid - 4096) * 256 + tid;   // 0..PE2R*64-1
    int rrow = idx >> 6, d = idx & 63;
    int u = rrow - 1088;
    int j = (u < 0) ? u + 2049 : u;       // in [0, 2048]
    float v = (j != 2048) ? pe_val(j, d) : 0.f;
    pe2[idx] = (f16)v;
  }
}

// ---------------- qv GEMM (64x64, 2-phase async pipeline) + D2x tail blocks ----------------
#define QV_STEP(T, AS, BS, CA0, CA1, CB0, CB1, NA0, NA1, NB0, NB1)             \
  {                                                                            \
    *(f16x8*)&AS[r * 72 + c] = CA0;                                            \
    *(f16x8*)&AS[r * 72 + c + 8] = CA1;                                        \
    *(f16x8*)&BS[r * 72 + c] = CB0;                                            \
    *(f16x8*)&BS[r * 72 + c + 8] = CB1;                                        \
    __syncthreads();                                                           \
    if ((T) + 1 < 16) {                                                        \
      const f16* na = ga + ((T) + 1) * 64;                                     \
      NA0 = *(const f16x8*)na;                                                 \
      NA1 = *(const f16x8*)(na + 8);                                           \
      const f16* nb = gb + ((T) + 1) * 64;                                     \
      NB0 = *(const f16x8*)nb;                                                 \
      NB1 = *(const f16x8*)(nb + 8);                                           \
    }                                                                          \
    _Pragma("unroll")                                                          \
    for (int kc = 0; kc < 2; ++kc) {                                           \
      f16x8 a = ld8(&AS[(w * 16 + li) * 72 + kc * 32 + g * 4]);                \
      _Pragma("unroll")                                                        \
      for (int nf = 0; nf < 4; ++nf) {                                         \
        f16x8 bfr = ld8(&BS[(nf * 16 + li) * 72 + kc * 32 + g * 4]);           \
        s[nf] = __builtin_amdgcn_mfma_f32_16x16x32_f16(a, bfr, s[nf], 0, 0, 0);\
      }                                                                        \
    }                                                                          \
  }

__global__ __launch_bounds__(256) void qv_mfma(const f16* __restrict__ xh,
                                               const f16* __restrict__ Wh,
                                               f16* __restrict__ qvh,
                                               f16* __restrict__ vT,
                                               const float* __restrict__ rr,
                                               const float* __restrict__ rw,
                                               const f16* __restrict__ pe2,
                                               float* __restrict__ D2x) {
  __shared__ f16 As0[64 * 72], As1[64 * 72];
  __shared__ f16 Bs0[64 * 72], Bs1[64 * 72];
  int tid = threadIdx.x;
  int bid = blockIdx.x;
  if (bid >= 1024) {
    // D2x tail: D2x[h][r] = (rw[h]-rr[h]) . pe2[r]
    int idx = (bid - 1024) * 256 + tid;
    if (idx < 16 * PE2R) {
      int h = idx / PE2R, r0 = idx - h * PE2R;
      float s = 0.f;
#pragma unroll
      for (int d = 0; d < HD; ++d)
        s = fmaf(rw[h * HD + d] - rr[h * HD + d], (float)pe2[r0 * HD + d], s);
      D2x[idx] = s;
    }
    return;
  }
  int w = tid >> 6, lane = tid & 63, g = lane >> 4, li = lane & 15;
  int m0 = (bid >> 5) * 64, n0 = (bid & 31) * 64;
  int r = tid >> 2, c = (tid & 3) * 16;

  const f16* ga = xh + (size_t)(m0 + r) * 1024 + c;
  const f16* gb = Wh + (size_t)(n0 + r) * 1024 + c;
  f16x8 ca0 = *(const f16x8*)ga, ca1 = *(const f16x8*)(ga + 8);
  f16x8 cb0 = *(const f16x8*)gb, cb1 = *(const f16x8*)(gb + 8);
  f16x8 na0, na1, nb0, nb1;

  f32x4 s[4];
#pragma unroll
  for (int i = 0; i < 4; ++i) s[i] = {0.f, 0.f, 0.f, 0.f};

  for (int t = 0; t < 16; t += 2) {
    QV_STEP(t, As0, Bs0, ca0, ca1, cb0, cb1, na0, na1, nb0, nb1);
    QV_STEP(t + 1, As1, Bs1, na0, na1, nb0, nb1, ca0, ca1, cb0, cb1);
  }

#pragma unroll
  for (int nf = 0; nf < 4; ++nf) {
    int n = n0 + nf * 16 + li;
#pragma unroll
    for (int rr2 = 0; rr2 < 4; ++rr2) {
      int m = m0 + w * 16 + g * 4 + rr2;
      f16 val = (f16)s[nf][rr2];
      if (n < 1024) {
        qvh[(size_t)m * 2048 + n] = val;
      } else {
        int b_ = m >> 10, ls = m & 1023, hd = n - 1024;
        vT[((size_t)(b_ * 16 + (hd >> 6)) * 64 + (hd & 63)) * 1024 + ls] = val;
      }
    }
  }
}

// ---------------- fused attention: rolling band, split-K x2, partial outputs ----------------
// Band G[u][q] = Qs(row)·pe_ext[u mod 2049] + D2x[h][u], row = q (u>=0) / q-1 (u<0);
// Qs carries +rr, D2x carries (rw-rr)·pe. Single Ks/Vs race-free with 2 barriers/step.
// Block (kh, bh, q0) covers k-tiles [8kh, 8kh+8); writes unnormalized O + (m,l).
#define BANDFILL(TT, QOFF, PEREG, D2V)                                         \
  {                                                                            \
    _Pragma("unroll")                                                          \
    for (int qf = 0; qf < 4; ++qf) {                                           \
      f32x4 gacc = {0.f, 0.f, 0.f, 0.f};                                       \
      _Pragma("unroll")                                                        \
      for (int kc = 0; kc < 2; ++kc) {                                         \
        f16x8 qo = ld8(&Qs[((QOFF) + qf * 16 + li) * 72 + kc * 32 + g * 4]);   \
        gacc = __builtin_amdgcn_mfma_f32_16x16x32_f16(PEREG[kc], qo, gacc, 0, 0, 0); \
      }                                                                        \
      f16x4 gpk;                                                               \
      gpk[0] = (f16)(gacc[0] + (D2V).x); gpk[1] = (f16)(gacc[1] + (D2V).y);    \
      gpk[2] = (f16)(gacc[2] + (D2V).z); gpk[3] = (f16)(gacc[3] + (D2V).w);    \
      *(f16x4*)&Gb[(qf * 16 + li) * GBS + (TT) + w * 16 + g * 4] = gpk;        \
    }                                                                          \
  }

#define ATTN_STEP(T, CK0, CK1, CV0, CV1, NK0, NK1, NV0, NV1, CPE, NPE)         \
  {                                                                            \
    const int k0 = (T) * 64;                                                   \
    const int tt = (64 * (T)) & 127;                                           \
    const int qoff = (64 * (T) >= q0) ? 1 : 0;                                 \
    *(f16x8*)&Ks[r * 72 + c] = CK0;                                            \
    *(f16x8*)&Ks[r * 72 + c + 8] = CK1;                                        \
    *(f16x8*)&Vs[r * 72 + c] = CV0;                                            \
    *(f16x8*)&Vs[r * 72 + c + 8] = CV1;                                        \
    float4 d2v = *(const float4*)(D2x + hD2 + 1088 + k0 - q0 + w * 16 + g * 4);\
    BANDFILL(tt, qoff, CPE, d2v)                                               \
    __syncthreads();                                                           \
    if ((T) + 1 < tend) {                                                      \
      const f16* nk = gk + (size_t)((T) + 1) * 64 * 1024;                      \
      NK0 = *(const f16x8*)nk;                                                 \
      NK1 = *(const f16x8*)(nk + 8);                                           \
      const f16* nv = gv + ((T) + 1) * 64;                                     \
      NV0 = *(const f16x8*)nv;                                                 \
      NV1 = *(const f16x8*)(nv + 8);                                           \
      const f16* pb = pe2 + (size_t)(1088 + 64 * ((T) + 1) - q0 + w * 16 + li) * 64; \
      NPE[0] = ld8(pb + g * 4);                                                \
      NPE[1] = ld8(pb + 32 + g * 4);                                           \
    }                                                                          \
    float gf[16];                                                              \
    {                                                                          \
      const int cb0 = tt + g * 4 - qi + 128;                                   \
      _Pragma("unroll")                                                        \
      for (int kf = 0; kf < 4; ++kf)                                           \
        _Pragma("unroll")                                                      \
        for (int u2 = 0; u2 < 4; ++u2)                                         \
          gf[kf * 4 + u2] = (float)Gb[qi * GBS + ((cb0 + kf * 16 + u2) & 127)];\
    }                                                                          \
    f32x4 s[4];                                                                \
    _Pragma("unroll")                                                          \
    for (int i = 0; i < 4; ++i) s[i] = {0.f, 0.f, 0.f, 0.f};                   \
    __builtin_amdgcn_s_setprio(1);                                             \
    _Pragma("unroll")                                                          \
    for (int kc = 0; kc < 2; ++kc) {                                           \
      f16x8 qb = ld8(&Qs[(1 + w * 16 + li) * 72 + kc * 32 + g * 4]);           \
      _Pragma("unroll")                                                        \
      for (int kf = 0; kf < 4; ++kf) {                                         \
        f16x8 ka = ld8(&Ks[(kf * 16 + li) * 72 + kc * 32 + g * 4]);            \
        s[kf] = __builtin_amdgcn_mfma_f32_16x16x32_f16(ka, qb, s[kf], 0, 0, 0);\
      }                                                                        \
    }                                                                          \
    __builtin_amdgcn_s_setprio(0);                                             \
    float sv[16];                                                              \
    float tmax = -1e30f;                                                       \
    _Pragma("unroll")                                                          \
    for (int kf = 0; kf < 4; ++kf) {                                           \
      _Pragma("unroll")                                                        \
      for (int rr2 = 0; rr2 < 4; ++rr2) {                                      \
        float v_ = s[kf][rr2] + gf[kf * 4 + rr2] +                             \
                   Ms[k0 + kf * 16 + g * 4 + rr2];                             \
        sv[kf * 4 + rr2] = v_;                                                 \
        tmax = fmaxf(tmax, v_);                                                \
      }                                                                        \
    }                                                                          \
    tmax = fmaxf(tmax, __shfl_xor(tmax, 16));                                  \
    tmax = fmaxf(tmax, __shfl_xor(tmax, 32));                                  \
    if (!__all(tmax <= m_run + 8.f)) {                                         \
      float mnew = fmaxf(m_run, tmax);                                         \
      float scale = __expf(m_run - mnew);                                      \
      m_run = mnew;                                                            \
      l_run *= scale;                                                          \
      _Pragma("unroll")                                                        \
      for (int f = 0; f < 4; ++f) {                                            \
        o[f][0] *= scale; o[f][1] *= scale; o[f][2] *= scale; o[f][3] *= scale;\
      }                                                                        \
    }                                                                          \
    float pf[16];                                                              \
    float lloc = 0.f;                                                          \
    _Pragma("unroll")                                                          \
    for (int i = 0; i < 16; ++i) { pf[i] = __expf(sv[i] - m_run); lloc += pf[i]; } \
    l_run += lloc;                                                             \
    f16x8 pb0, pb1;                                                            \
    _Pragma("unroll")                                                          \
    for (int i = 0; i < 8; ++i) { pb0[i] = (f16)pf[i]; pb1[i] = (f16)pf[8 + i]; } \
    __builtin_amdgcn_s_setprio(1);                                             \
    _Pragma("unroll")                                                          \
    for (int f = 0; f < 4; ++f) {                                              \
      f16x8 va0 = ld8(&Vs[(f * 16 + li) * 72 + g * 4]);                        \
      o[f] = __builtin_amdgcn_mfma_f32_16x16x32_f16(va0, pb0, o[f], 0, 0, 0);  \
      f16x8 va1 = ld8(&Vs[(f * 16 + li) * 72 + 32 + g * 4]);                   \
      o[f] = __builtin_amdgcn_mfma_f32_16x16x32_f16(va1, pb1, o[f], 0, 0, 0);  \
    }                                                                          \
    __builtin_amdgcn_s_setprio(0);                                             \
    __syncthreads();                                                           \
  }

__global__ __launch_bounds__(256) void attn_mfma(const f16* __restrict__ xh,
                                                 const f16* __restrict__ qvh,
                                                 const f16* __restrict__ vT,
                                                 const f16* __restrict__ pe2,
                                                 const float* __restrict__ D2x,
                                                 const int* __restrict__ mask,
                                                 const float* __restrict__ rr,
                                                 float* __restrict__ opart,
                                                 float* __restrict__ mlbuf) {
  __shared__ f16 Qs[65 * 72];            // rows q0-1 .. q0+63 (+rr)
  __shared__ f16 Ks[64 * 72], Vs[64 * 72];
  __shared__ f16 Gb[64 * GBS];           // circular band [qlocal][128 cols + pad]
  __shared__ float Ms[L_SEQ];
  int tid = threadIdx.x;
  int w = tid >> 6, lane = tid & 63, g = lane >> 4, li = lane & 15;
  int bid = blockIdx.x;
  int bid9 = bid & 511;
  int kh = bid >> 9;                      // k-half
  int swz = (bid9 & 7) * 64 + (bid9 >> 3);  // XCD swizzle on low 9 bits
  int q0 = (swz & 15) * 64;
  int bh = swz >> 4;
  int b = bh >> 4, h = bh & 15;
  int r = tid >> 2, c = (tid & 3) * 16;
  const int qi = w * 16 + li;
  const int hD2 = h * PE2R;
  const int t0 = kh * 8, tend = t0 + 8;

  // additive mask vector
#pragma unroll
  for (int i = 0; i < 4; ++i) {
    int k = tid + i * 256;
    Ms[k] = mask[b * L_SEQ + k] ? 0.f : -1e30f;
  }
  // Q rows q0-1 .. q0+63 (+rr); row 0 clamped (never gathered for q0=0)
  {
    int gq = q0 - 1 + r;
    if (gq < 0) gq = 0;
    const f16* src = qvh + (size_t)(b * L_SEQ + gq) * 2048 + h * HD + c;
#pragma unroll
    for (int u = 0; u < 16; ++u)
      Qs[r * 72 + c + u] = (f16)((float)src[u] + rr[h * HD + c + u]);
    if (tid < 4) {
      int c2 = tid * 16;
      const f16* s2 = qvh + (size_t)(b * L_SEQ + q0 + 63) * 2048 + h * HD + c2;
#pragma unroll
      for (int u = 0; u < 16; ++u)
        Qs[64 * 72 + c2 + u] = (f16)((float)s2[u] + rr[h * HD + c2 + u]);
    }
  }

  // global prefetches: K/V tile t0, pe strips for prologue and tile-t0 windows
  const f16* gk = xh + (size_t)(b * L_SEQ + r) * 1024 + h * HD + c;
  const f16* gv = vT + ((size_t)bh * 64 + r) * 1024 + c;
  f16x8 cka = *(const f16x8*)(gk + (size_t)t0 * 64 * 1024);
  f16x8 ckb = *(const f16x8*)(gk + (size_t)t0 * 64 * 1024 + 8);
  f16x8 cva = *(const f16x8*)(gv + t0 * 64);
  f16x8 cvb = *(const f16x8*)(gv + t0 * 64 + 8);
  f16x8 nka, nkb, nva, nvb;
  f16x8 peP[2], peA[2], peB[2];
  {
    // prologue: u base 64*t0 - q0 - 64
    const f16* pp = pe2 + (size_t)(1024 + 64 * t0 - q0 + w * 16 + li) * 64;
    peP[0] = ld8(pp + g * 4);
    peP[1] = ld8(pp + 32 + g * 4);
    // tile t0: u base 64*t0 - q0
    const f16* p0 = pe2 + (size_t)(1088 + 64 * t0 - q0 + w * 16 + li) * 64;
    peA[0] = ld8(p0 + g * 4);
    peA[1] = ld8(p0 + 32 + g * 4);
  }

  __syncthreads();   // Qs/Ms ready

  // prologue band: window [64*t0-q0-64, 64*t0-q0) -> cols 64..127 (TT=(64*(t0-1))&127=64)
  {
    const int qoffP = (64 * (t0 - 1) >= q0) ? 1 : 0;
    float4 d2p = *(const float4*)(D2x + hD2 + 1024 + 64 * t0 - q0 + w * 16 + g * 4);
    BANDFILL(64, qoffP, peP, d2p)
  }
  // (no barrier needed: step t0's mid-barrier covers Gb visibility)

  float m_run = -1e30f, l_run = 0.f;
  f32x4 o[4];
#pragma unroll
  for (int i = 0; i < 4; ++i) o[i] = {0.f, 0.f, 0.f, 0.f};

  for (int t = t0; t < tend; t += 2) {
    ATTN_STEP(t, cka, ckb, cva, cvb, nka, nkb, nva, nvb, peA, peB);
    ATTN_STEP(t + 1, nka, nkb, nva, nvb, cka, ckb, cva, cvb, peB, peA);
  }

  float lt = l_run;
  lt += __shfl_xor(lt, 16);
  lt += __shfl_xor(lt, 32);
  int qrow = q0 + qi;
  size_t prow = (size_t)(kh * 32 + bh) * L_SEQ + qrow;
  float* op = opart + prow * 64;
#pragma unroll
  for (int f = 0; f < 4; ++f) {
    float4 res = {o[f][0], o[f][1], o[f][2], o[f][3]};
    *(float4*)(op + f * 16 + g * 4) = res;
  }
  if (g == 0) {
    mlbuf[prow * 2] = m_run;
    mlbuf[prow * 2 + 1] = lt;
  }
}

// ---------------- combine the two K-halves ----------------
__global__ __launch_bounds__(256) void combine(const float* __restrict__ opart,
                                               const float* __restrict__ mlbuf,
                                               float* __restrict__ out) {
  int gid = blockIdx.x * 256 + threadIdx.x;
  int e = gid * 4;                     // over 32768*64 floats
  int qh = e >> 6;                     // bh*1024 + q
  int d0 = e & 63;
  float m0v = mlbuf[(size_t)qh * 2], l0v = mlbuf[(size_t)qh * 2 + 1];
  float m1v = mlbuf[(size_t)(32768 + qh) * 2], l1v = mlbuf[(size_t)(32768 + qh) * 2 + 1];
  float4 o0 = *(const float4*)(opart + (size_t)qh * 64 + d0);
  float4 o1 = *(const float4*)(opart + (size_t)(32768 + qh) * 64 + d0);
  float M = fmaxf(m0v, m1v);
  float w0 = __expf(m0v - M), w1 = __expf(m1v - M);
  float inv = 1.0f / (l0v * w0 + l1v * w1);
  int bh = qh >> 10, q = qh & 1023;
  int b = bh >> 4, h = bh & 15;
  float4 res = {(o0.x * w0 + o1.x * w1) * inv, (o0.y * w0 + o1.y * w1) * inv,
                (o0.z * w0 + o1.z * w1) * inv, (o0.w * w0 + o1.w * w1) * inv};
  *(float4*)(out + (size_t)(b * L_SEQ + q) * DM + h * HD + d0) = res;
}

extern "C" void kernel_launch(void* const* d_in, const int* in_sizes, int n_in,
                              void* d_out, int out_size, void* d_ws, size_t ws_size,
                              hipStream_t stream) {
  const float* x = (const float*)d_in[0];
  const int* mask = (const int*)d_in[1];
  const float* W = (const float*)d_in[2];
  const float* rr = (const float*)d_in[3];
  const float* rw = (const float*)d_in[4];
  float* out = (float*)d_out;

  f16* pe2 = (f16*)d_ws;                             // 2176*64 f16
  float* D2x = (float*)(pe2 + (size_t)PE2R * 64);    // 16*2176 f32
  f16* xh = (f16*)(D2x + 16 * PE2R);                 // 2M f16
  f16* Wh = xh + 2097152;                            // 2M f16
  f16* qvh = Wh + 2097152;                           // 4M f16
  f16* vT = qvh + 4194304;                           // 2M f16
  float* opart = (float*)(vT + 2097152);             // 2*32768*64 f32
  float* mlbuf = opart + 4194304;                    // 2*32768*2 f32

  prep1<<<4096 + (PE2R * 64) / 256, 256, 0, stream>>>(x, W, pe2, xh, Wh);
  qv_mfma<<<1024 + (16 * PE2R + 255) / 256, 256, 0, stream>>>(xh, Wh, qvh, vT, rr, rw, pe2, D2x);
  attn_mfma<<<1024, 256, 0, stream>>>(xh, qvh, vT, pe2, D2x, mask, rr, opart, mlbuf);
  combine<<<2048, 256, 0, stream>>>(opart, mlbuf, out);
}

// Round 17
// 79.650 us; speedup vs baseline: 1.2292x; 1.2292x over previous
//
#include <hip/hip_runtime.h>
#include <hip/hip_bf16.h>
#include <math.h>

#define L_SEQ 1024
#define TWO_L 2048
#define NHEAD 16
#define HD 64
#define DM 1024
#define BATCH 2
// pe2: 2176 rows, row r <-> u = r-1088, value = pe_ext[u mod 2049];
// pe_ext[j] = pe[j] for j<2048, pe_ext[2048] = 0 (shifted-diagonal zero row).
#define PE2R 2176
#define GBS 132

typedef _Float16 f16;
typedef _Float16 f16x4 __attribute__((ext_vector_type(4)));
typedef _Float16 f16x8 __attribute__((ext_vector_type(8)));
typedef float f32x4 __attribute__((ext_vector_type(4)));

__device__ __forceinline__ f16x8 ld8(const f16* p) {
  f16x4 lo = *(const f16x4*)p;
  f16x4 hi = *(const f16x4*)(p + 16);
  f16x8 r;
  r[0] = lo[0]; r[1] = lo[1]; r[2] = lo[2]; r[3] = lo[3];
  r[4] = hi[0]; r[5] = hi[1]; r[6] = hi[2]; r[7] = hi[3];
  return r;
}

__device__ __forceinline__ float pe_val(int j, int d) {
  float posval = (float)(j - L_SEQ);
  float freq = expf(-(float)(d & 31) * 0.2971077539347156f);  // ln(10000)/31
  float ang = posval * freq;
  return (d < 32) ? sinf(ang) : cosf(ang);
}

// ---------------- prep1: cvt x, cvt W, pe2 extended table ----------------
__global__ __launch_bounds__(256) void prep1(const float* __restrict__ x,
                                             const float* __restrict__ W,
                                             f16* __restrict__ pe2,
                                             f16* __restrict__ xh,
                                             f16* __restrict__ Wh) {
  int bid = blockIdx.x, tid = threadIdx.x;
  if (bid < 2048) {
    int i = (bid * 256 + tid) * 4;
    float4 v = *(const float4*)(x + i);
    f16x4 o = {(f16)v.x, (f16)v.y, (f16)v.z, (f16)v.w};
    *(f16x4*)(xh + i) = o;
  } else if (bid < 4096) {
    int i = ((bid - 2048) * 256 + tid) * 4;
    float4 v = *(const float4*)(W + i);
    f16x4 o = {(f16)v.x, (f16)v.y, (f16)v.z, (f16)v.w};
    *(f16x4*)(Wh + i) = o;
  } else {
    int idx = (bid - 4096) * 256 + tid;   // 0..PE2R*64-1
    int rrow = idx >> 6, d = idx & 63;
    int u = rrow - 1088;
    int j = (u < 0) ? u + 2049 : u;       // in [0, 2048]
    float v = (j != 2048) ? pe_val(j, d) : 0.f;
    pe2[idx] = (f16)v;
  }
}

// ---------------- qv GEMM: 128x64 tiles, 2-phase async pipeline ----------------
#define QV_STEP(T, AS, BS, CA0, CA1, CA2, CA3, CB0, CB1, NA0, NA1, NA2, NA3, NB0, NB1) \
  {                                                                            \
    *(f16x8*)&AS[ra * 72 + ca] = CA0;                                          \
    *(f16x8*)&AS[ra * 72 + ca + 8] = CA1;                                      \
    *(f16x8*)&AS[ra * 72 + ca + 16] = CA2;                                     \
    *(f16x8*)&AS[ra * 72 + ca + 24] = CA3;                                     \
    *(f16x8*)&BS[rb * 72 + cb] = CB0;                                          \
    *(f16x8*)&BS[rb * 72 + cb + 8] = CB1;                                      \
    __syncthreads();                                                           \
    if ((T) + 1 < 16) {                                                        \
      const f16* na = ga + ((T) + 1) * 64;                                     \
      NA0 = *(const f16x8*)na;                                                 \
      NA1 = *(const f16x8*)(na + 8);                                           \
      NA2 = *(const f16x8*)(na + 16);                                          \
      NA3 = *(const f16x8*)(na + 24);                                          \
      const f16* nb = gb + ((T) + 1) * 64;                                     \
      NB0 = *(const f16x8*)nb;                                                 \
      NB1 = *(const f16x8*)(nb + 8);                                           \
    }                                                                          \
    __builtin_amdgcn_s_setprio(1);                                             \
    _Pragma("unroll")                                                          \
    for (int kc = 0; kc < 2; ++kc) {                                           \
      f16x8 am0 = ld8(&AS[(w * 32 + li) * 72 + kc * 32 + g * 4]);              \
      f16x8 am1 = ld8(&AS[(w * 32 + 16 + li) * 72 + kc * 32 + g * 4]);         \
      _Pragma("unroll")                                                        \
      for (int nf = 0; nf < 4; ++nf) {                                         \
        f16x8 bfr = ld8(&BS[(nf * 16 + li) * 72 + kc * 32 + g * 4]);           \
        s[0][nf] = __builtin_amdgcn_mfma_f32_16x16x32_f16(am0, bfr, s[0][nf], 0, 0, 0); \
        s[1][nf] = __builtin_amdgcn_mfma_f32_16x16x32_f16(am1, bfr, s[1][nf], 0, 0, 0); \
      }                                                                        \
    }                                                                          \
    __builtin_amdgcn_s_setprio(0);                                             \
  }

__global__ __launch_bounds__(256) void qv_mfma(const f16* __restrict__ xh,
                                               const f16* __restrict__ Wh,
                                               f16* __restrict__ qvh,
                                               f16* __restrict__ vT) {
  __shared__ f16 As0[128 * 72], As1[128 * 72];
  __shared__ f16 Bs0[64 * 72], Bs1[64 * 72];
  int tid = threadIdx.x;
  int w = tid >> 6, lane = tid & 63, g = lane >> 4, li = lane & 15;
  int m0 = blockIdx.y * 128, n0 = blockIdx.x * 64;
  int ra = tid >> 1, ca = (tid & 1) * 32;
  int rb = tid >> 2, cb = (tid & 3) * 16;

  const f16* ga = xh + (size_t)(m0 + ra) * 1024 + ca;
  const f16* gb = Wh + (size_t)(n0 + rb) * 1024 + cb;
  f16x8 ca0 = *(const f16x8*)ga, ca1 = *(const f16x8*)(ga + 8);
  f16x8 ca2 = *(const f16x8*)(ga + 16), ca3 = *(const f16x8*)(ga + 24);
  f16x8 cb0 = *(const f16x8*)gb, cb1 = *(const f16x8*)(gb + 8);
  f16x8 na0, na1, na2, na3, nb0, nb1;

  f32x4 s[2][4];
#pragma unroll
  for (int i = 0; i < 2; ++i)
#pragma unroll
    for (int j = 0; j < 4; ++j) s[i][j] = {0.f, 0.f, 0.f, 0.f};

  for (int t = 0; t < 16; t += 2) {
    QV_STEP(t, As0, Bs0, ca0, ca1, ca2, ca3, cb0, cb1, na0, na1, na2, na3, nb0, nb1);
    QV_STEP(t + 1, As1, Bs1, na0, na1, na2, na3, nb0, nb1, ca0, ca1, ca2, ca3, cb0, cb1);
  }

#pragma unroll
  for (int mb = 0; mb < 2; ++mb) {
#pragma unroll
    for (int nf = 0; nf < 4; ++nf) {
      int n = n0 + nf * 16 + li;
#pragma unroll
      for (int rr2 = 0; rr2 < 4; ++rr2) {
        int m = m0 + w * 32 + mb * 16 + g * 4 + rr2;
        f16 val = (f16)s[mb][nf][rr2];
        if (n < 1024) {
          qvh[(size_t)m * 2048 + n] = val;
        } else {
          int b_ = m >> 10, ls = m & 1023, hd = n - 1024;
          vT[((size_t)(b_ * 16 + (hd >> 6)) * 64 + (hd & 63)) * 1024 + ls] = val;
        }
      }
    }
  }
}

// ---------------- fused attention with rolling 64-wide relative-position band ----------------
// (R12 verbatim) Band G[u][q] = (q_vec(row)+rw).pe_ext[u mod 2049], row = q for u>=0,
// q-1 for u<0. Circular Gb[64q][GBS], col(u) = (u+q0)&127. Per k-tile t: fill window
// u in [64t-q0, 64t-q0+64) -> cols (64t&127)+[0,64). Prologue fills [-q0-64, -q0).
#define BANDFILL(TT, QOFF, PEREG)                                              \
  {                                                                            \
    _Pragma("unroll")                                                          \
    for (int qf = 0; qf < 4; ++qf) {                                           \
      f32x4 gacc = {0.f, 0.f, 0.f, 0.f};                                       \
      _Pragma("unroll")                                                        \
      for (int kc = 0; kc < 2; ++kc) {                                         \
        f16x8 qo = ld8(&Qw[((QOFF) + qf * 16 + li) * 72 + kc * 32 + g * 4]);   \
        gacc = __builtin_amdgcn_mfma_f32_16x16x32_f16(PEREG[kc], qo, gacc, 0, 0, 0); \
      }                                                                        \
      f16x4 gpk;                                                               \
      gpk[0] = (f16)gacc[0]; gpk[1] = (f16)gacc[1];                            \
      gpk[2] = (f16)gacc[2]; gpk[3] = (f16)gacc[3];                            \
      *(f16x4*)&Gb[(qf * 16 + li) * GBS + (TT) + w * 16 + g * 4] = gpk;        \
    }                                                                          \
  }

#define ATTN_STEP(T, KS, VS, CK0, CK1, CV0, CV1, NK0, NK1, NV0, NV1, CPE, NPE) \
  {                                                                            \
    const int k0 = (T) * 64;                                                   \
    const int tt = (64 * (T)) & 127;                                           \
    const int qoff = (64 * (T) >= q0) ? 1 : 0;                                 \
    *(f16x8*)&KS[r * 72 + c] = CK0;                                            \
    *(f16x8*)&KS[r * 72 + c + 8] = CK1;                                        \
    *(f16x8*)&VS[r * 72 + c] = CV0;                                            \
    *(f16x8*)&VS[r * 72 + c + 8] = CV1;                                        \
    BANDFILL(tt, qoff, CPE)                                                    \
    __syncthreads();                                                           \
    if ((T) + 1 < 16) {                                                        \
      const f16* nk = gk + (size_t)((T) + 1) * 64 * 1024;                      \
      NK0 = *(const f16x8*)nk;                                                 \
      NK1 = *(const f16x8*)(nk + 8);                                           \
      const f16* nv = gv + ((T) + 1) * 64;                                     \
      NV0 = *(const f16x8*)nv;                                                 \
      NV1 = *(const f16x8*)(nv + 8);                                           \
      const f16* pb = pe2 + (size_t)(1088 + 64 * ((T) + 1) - q0 + w * 16 + li) * 64; \
      NPE[0] = ld8(pb + g * 4);                                                \
      NPE[1] = ld8(pb + 32 + g * 4);                                           \
    }                                                                          \
    float gf[16];                                                              \
    {                                                                          \
      const int cb0 = tt + g * 4 - qi + 128;                                   \
      _Pragma("unroll")                                                        \
      for (int kf = 0; kf < 4; ++kf)                                           \
        _Pragma("unroll")                                                      \
        for (int u2 = 0; u2 < 4; ++u2)                                         \
          gf[kf * 4 + u2] = (float)Gb[qi * GBS + ((cb0 + kf * 16 + u2) & 127)];\
    }                                                                          \
    f32x4 s[4];                                                                \
    _Pragma("unroll")                                                          \
    for (int i = 0; i < 4; ++i) s[i] = {0.f, 0.f, 0.f, 0.f};                   \
    __builtin_amdgcn_s_setprio(1);                                             \
    _Pragma("unroll")                                                          \
    for (int kc = 0; kc < 2; ++kc) {                                           \
      f16x8 qb = ld8(&Qs[(1 + w * 16 + li) * 72 + kc * 32 + g * 4]);           \
      _Pragma("unroll")                                                        \
      for (int kf = 0; kf < 4; ++kf) {                                         \
        f16x8 ka = ld8(&KS[(kf * 16 + li) * 72 + kc * 32 + g * 4]);            \
        s[kf] = __builtin_amdgcn_mfma_f32_16x16x32_f16(ka, qb, s[kf], 0, 0, 0);\
      }                                                                        \
    }                                                                          \
    __builtin_amdgcn_s_setprio(0);                                             \
    float sv[16];                                                              \
    float tmax = -1e30f;                                                       \
    _Pragma("unroll")                                                          \
    for (int kf = 0; kf < 4; ++kf) {                                           \
      _Pragma("unroll")                                                        \
      for (int rr2 = 0; rr2 < 4; ++rr2) {                                      \
        float v_ = s[kf][rr2] + gf[kf * 4 + rr2] +                             \
                   Ms[k0 + kf * 16 + g * 4 + rr2];                             \
        sv[kf * 4 + rr2] = v_;                                                 \
        tmax = fmaxf(tmax, v_);                                                \
      }                                                                        \
    }                                                                          \
    tmax = fmaxf(tmax, __shfl_xor(tmax, 16));                                  \
    tmax = fmaxf(tmax, __shfl_xor(tmax, 32));                                  \
    if (!__all(tmax <= m_run + 8.f)) {                                         \
      float mnew = fmaxf(m_run, tmax);                                         \
      float scale = __expf(m_run - mnew);                                      \
      m_run = mnew;                                                            \
      l_run *= scale;                                                          \
      _Pragma("unroll")                                                        \
      for (int f = 0; f < 4; ++f) {                                            \
        o[f][0] *= scale; o[f][1] *= scale; o[f][2] *= scale; o[f][3] *= scale;\
      }                                                                        \
    }                                                                          \
    float pf[16];                                                              \
    float lloc = 0.f;                                                          \
    _Pragma("unroll")                                                          \
    for (int i = 0; i < 16; ++i) { pf[i] = __expf(sv[i] - m_run); lloc += pf[i]; } \
    l_run += lloc;                                                             \
    f16x8 pb0, pb1;                                                            \
    _Pragma("unroll")                                                          \
    for (int i = 0; i < 8; ++i) { pb0[i] = (f16)pf[i]; pb1[i] = (f16)pf[8 + i]; } \
    __builtin_amdgcn_s_setprio(1);                                             \
    _Pragma("unroll")                                                          \
    for (int f = 0; f < 4; ++f) {                                              \
      f16x8 va0 = ld8(&VS[(f * 16 + li) * 72 + g * 4]);                        \
      o[f] = __builtin_amdgcn_mfma_f32_16x16x32_f16(va0, pb0, o[f], 0, 0, 0);  \
      f16x8 va1 = ld8(&VS[(f * 16 + li) * 72 + 32 + g * 4]);                   \
      o[f] = __builtin_amdgcn_mfma_f32_16x16x32_f16(va1, pb1, o[f], 0, 0, 0);  \
    }                                                                          \
    __builtin_amdgcn_s_setprio(0);                                             \
    __syncthreads();                                                           \
  }

__global__ __launch_bounds__(256) void attn_mfma(const f16* __restrict__ xh,
                                                 const f16* __restrict__ qvh,
                                                 const f16* __restrict__ vT,
                                                 const f16* __restrict__ pe2,
                                                 const int* __restrict__ mask,
                                                 const float* __restrict__ rr,
                                                 const float* __restrict__ rw,
                                                 float* __restrict__ out) {
  __shared__ f16 Qs[65 * 72];            // rows q0-1 .. q0+63, +r_r bias (QK^T)
  __shared__ f16 Qw[65 * 72];            // rows q0-1 .. q0+63, +r_w bias (band)
  __shared__ f16 Ks0[64 * 72], Ks1[64 * 72];
  __shared__ f16 Vs0[64 * 72], Vs1[64 * 72];
  __shared__ f16 Gb[64 * GBS];           // circular band [qlocal][128 cols + pad]
  __shared__ float Ms[L_SEQ];
  int tid = threadIdx.x;
  int w = tid >> 6, lane = tid & 63, g = lane >> 4, li = lane & 15;
  int bid = blockIdx.x;
  int swz = (bid & 7) * 64 + (bid >> 3);  // XCD swizzle: 4 bh (64 q-blk) per XCD
  int q0 = (swz & 15) * 64;
  int bh = swz >> 4;
  int b = bh >> 4, h = bh & 15;
  int r = tid >> 2, c = (tid & 3) * 16;
  const int qi = w * 16 + li;

  // additive mask vector
#pragma unroll
  for (int i = 0; i < 4; ++i) {
    int k = tid + i * 256;
    Ms[k] = mask[b * L_SEQ + k] ? 0.f : -1e30f;
  }
  // Q rows q0-1 .. q0+63: Qs = +rr (row i <-> q0-1+i), Qw = +rw. Row 0 clamped
  // (its band values correspond to k<0 and are never gathered).
  {
    int gq = q0 - 1 + r;
    if (gq < 0) gq = 0;
    const f16* src = qvh + (size_t)(b * L_SEQ + gq) * 2048 + h * HD + c;
#pragma unroll
    for (int u = 0; u < 16; ++u) {
      float v = (float)src[u];
      Qs[r * 72 + c + u] = (f16)(v + rr[h * HD + c + u]);
      Qw[r * 72 + c + u] = (f16)(v + rw[h * HD + c + u]);
    }
    if (tid < 4) {
      int c2 = tid * 16;
      const f16* s2 = qvh + (size_t)(b * L_SEQ + q0 + 63) * 2048 + h * HD + c2;
#pragma unroll
      for (int u = 0; u < 16; ++u) {
        float v = (float)s2[u];
        Qs[64 * 72 + c2 + u] = (f16)(v + rr[h * HD + c2 + u]);
        Qw[64 * 72 + c2 + u] = (f16)(v + rw[h * HD + c2 + u]);
      }
    }
  }

  // global prefetches: K/V tile 0, pe strips for prologue window and tile-0 window
  const f16* gk = xh + (size_t)(b * L_SEQ + r) * 1024 + h * HD + c;
  const f16* gv = vT + ((size_t)bh * 64 + r) * 1024 + c;
  f16x8 cka = *(const f16x8*)gk, ckb = *(const f16x8*)(gk + 8);
  f16x8 cva = *(const f16x8*)gv, cvb = *(const f16x8*)(gv + 8);
  f16x8 nka, nkb, nva, nvb;
  f16x8 peP[2], peA[2], peB[2];
  {
    const f16* pp = pe2 + (size_t)(1024 - q0 + w * 16 + li) * 64;   // prologue: u base -q0-64
    peP[0] = ld8(pp + g * 4);
    peP[1] = ld8(pp + 32 + g * 4);
    const f16* p0 = pe2 + (size_t)(1088 - q0 + w * 16 + li) * 64;   // tile 0: u base -q0
    peA[0] = ld8(p0 + g * 4);
    peA[1] = ld8(p0 + 32 + g * 4);
  }

  __syncthreads();   // Qs/Qw/Ms ready

  // prologue band: window [-q0-64, -q0) -> cols 64..127, wrap rows (qoff=0)
  BANDFILL(64, 0, peP)
  // (no barrier needed here: step 0's barrier covers Gb visibility)

  float m_run = -1e30f, l_run = 0.f;
  f32x4 o[4];
#pragma unroll
  for (int i = 0; i < 4; ++i) o[i] = {0.f, 0.f, 0.f, 0.f};

  for (int t = 0; t < 16; t += 2) {
    ATTN_STEP(t, Ks0, Vs0, cka, ckb, cva, cvb, nka, nkb, nva, nvb, peA, peB);
    ATTN_STEP(t + 1, Ks1, Vs1, nka, nkb, nva, nvb, cka, ckb, cva, cvb, peB, peA);
  }

  float lt = l_run;
  lt += __shfl_xor(lt, 16);
  lt += __shfl_xor(lt, 32);
  float inv = 1.0f / lt;
  int qrow = q0 + qi;
  float* op = out + ((size_t)(b * L_SEQ + qrow)) * DM + h * HD;
#pragma unroll
  for (int f = 0; f < 4; ++f) {
    float4 res = {o[f][0] * inv, o[f][1] * inv, o[f][2] * inv, o[f][3] * inv};
    *(float4*)(op + f * 16 + g * 4) = res;
  }
}

extern "C" void kernel_launch(void* const* d_in, const int* in_sizes, int n_in,
                              void* d_out, int out_size, void* d_ws, size_t ws_size,
                              hipStream_t stream) {
  const float* x = (const float*)d_in[0];
  const int* mask = (const int*)d_in[1];
  const float* W = (const float*)d_in[2];
  const float* rr = (const float*)d_in[3];
  const float* rw = (const float*)d_in[4];
  float* out = (float*)d_out;

  f16* pe2 = (f16*)d_ws;                             // 2176*64 f16
  f16* xh = pe2 + (size_t)PE2R * 64;                 // 2M f16
  f16* Wh = xh + 2097152;                            // 2M f16
  f16* qvh = Wh + 2097152;                           // 4M f16
  f16* vT = qvh + 4194304;                           // 2M f16

  prep1<<<4096 + (PE2R * 64) / 256, 256, 0, stream>>>(x, W, pe2, xh, Wh);
  qv_mfma<<<dim3(32, 16), 256, 0, stream>>>(xh, Wh, qvh, vT);
  attn_mfma<<<512, 256, 0, stream>>>(xh, qvh, vT, pe2, mask, rr, rw, out);
}